// Round 14
// baseline (10909.339 us; speedup 1.0000x reference)
//
#include <hip/hip_runtime.h>
#include <stdint.h>
#include <stddef.h>

#define T_ 512
#define B_ 128
#define D_ 400
#define H_ 400
#define HP 416
#define GP 1664            // 4*HP (per-dir padded gate dim)
#define NW 3328            // both dirs stacked
#define KXP 832            // uniform padded x-K for all layers
#define NTILES 13          // h tiles of 32 per dir
#define NGRP 8             // batch groups of 16
#define REC_BLOCKS 208     // 2*8*13
#define PAIRS 208          // 416 cols / 2 per batch row (u64 slots)

// GC float stride
#define GC_FSTRIDE 576     // 16*36

// tagged h buffer: [16 cid][2 parity][16 batch][208 pair] u64
#define HBT_U64   ((size_t)16*2*16*PAIRS)
#define HBT_BYTES (HBT_U64*8)

// Whh register-fragment blob: [2 dir][13 tile][4 gate][2 ch][13 kk][64 lane][8]
#define WHHR_US8  ((size_t)2*13*4*2*13*64)
#define WHHR_BYTES (WHHR_US8*8*2)
// Wih register-fragment blob: [2 dir][13 tile][4 gate][2 ch][26 kk][64 lane][8]
#define WIHR_US8  ((size_t)2*13*4*2*26*64)
#define WIHR_BYTES (WIHR_US8*8*2)

typedef __attribute__((ext_vector_type(8))) __bf16 bf16x8;
typedef __attribute__((ext_vector_type(4))) float f32x4;
typedef __attribute__((ext_vector_type(8))) unsigned short us8;

__device__ __forceinline__ unsigned short f2bf(float f){
  unsigned u = __builtin_bit_cast(unsigned, f);
  u = (u + 0x7FFFu + ((u >> 16) & 1u)) >> 16;
  return (unsigned short)u;
}
__device__ __forceinline__ float bf2f(unsigned short s){
  unsigned u = ((unsigned)s) << 16;
  return __builtin_bit_cast(float, u);
}
__device__ __forceinline__ float sigm(float x){ return 1.f / (1.f + __expf(-x)); }
__device__ __forceinline__ float tanh_f(float x){
  float ax = fabsf(x);
  float e = __expf(-2.f * ax);
  float t = (1.f - e) / (1.f + e);
  return x < 0.f ? -t : t;
}

// agent-scope relaxed atomics == MALL-coherent accesses, NO cache maintenance
__device__ __forceinline__ void h_store_u64(unsigned long long* p, unsigned long long v){
  __hip_atomic_store(p, v, __ATOMIC_RELAXED, __HIP_MEMORY_SCOPE_AGENT);
}
__device__ __forceinline__ unsigned long long h_load_u64(const unsigned long long* p){
  return __hip_atomic_load(p, __ATOMIC_RELAXED, __HIP_MEMORY_SCOPE_AGENT);
}

// ======================= prep kernels =======================
__global__ void k_conv_x0(const float* __restrict__ x, unsigned short* __restrict__ xa){
  const size_t i = (size_t)blockIdx.x*256 + threadIdx.x;
  if (i >= (size_t)T_*B_*KXP) return;
  const int k = (int)(i % KXP);
  const size_t tb = i / KXP;
  xa[i] = f2bf(k < D_ ? x[tb*D_ + k] : 0.f);
}

// Wih -> MFMA B-fragments [2 dir][13 tile][4 gate][2 ch][26 kk][64 lane][8]
__global__ void k_prep_wihR(const float* __restrict__ wf, const float* __restrict__ wb,
                            int mode, unsigned short* __restrict__ dst){
  const size_t i = (size_t)blockIdx.x*256 + threadIdx.x;
  if (i >= WIHR_US8) return;
  const int lane = (int)(i & 63);
  size_t q = i >> 6;
  const int kk = (int)(q % 26); q /= 26;
  const int ch = (int)(q % 2);  q /= 2;
  const int g  = (int)(q % 4);  q /= 4;
  const int tile = (int)(q % 13);
  const int dirx = (int)(q / 13);
  const int c  = tile*32 + ch*16 + (lane & 15);
  const int k0 = kk*32 + (lane >> 4)*8;
  const float* W = dirx ? wb : wf;
  const int stride = mode ? 800 : D_;
  unsigned short v[8];
  #pragma unroll
  for (int e = 0; e < 8; ++e){
    const int k = k0 + e;
    int ks;
    if (mode == 0) ks = (k < D_) ? k : -1;
    else           ks = (k < 400) ? k : ((k >= 416 && k < 816) ? (k - 16) : -1);
    const float x = (c < H_ && ks >= 0) ? W[(size_t)(g*H_ + c)*stride + ks] : 0.f;
    v[e] = f2bf(x);
  }
  *(us8*)(dst + i*8) = *(const us8*)v;
}

// Whh -> B-fragments (R7-verified layout)
__global__ void k_prep_whhR(const float* __restrict__ wf, const float* __restrict__ wb,
                            unsigned short* __restrict__ dst){
  const size_t i = (size_t)blockIdx.x*256 + threadIdx.x;
  if (i >= WHHR_US8) return;
  const int lane = (int)(i & 63);
  size_t q = i >> 6;
  const int kk = (int)(q % 13); q /= 13;
  const int ch = (int)(q % 2);  q /= 2;
  const int w  = (int)(q % 4);  q /= 4;
  const int tile = (int)(q % 13);
  const int dirx = (int)(q / 13);
  const int c  = tile*32 + ch*16 + (lane & 15);
  const int k0 = kk*32 + (lane >> 4)*8;
  const float* W = dirx ? wb : wf;
  unsigned short v[8];
  #pragma unroll
  for (int e = 0; e < 8; ++e){
    const int k = k0 + e;
    const float x = (c < H_ && k < H_) ? W[(size_t)(w*H_ + c)*H_ + k] : 0.f;
    v[e] = f2bf(x);
  }
  *(us8*)(dst + i*8) = *(const us8*)v;
}

__global__ void k_prep_bias(const float* __restrict__ bsf, const float* __restrict__ bsb,
                            float* __restrict__ dst){
  const int n = blockIdx.x*256 + threadIdx.x;
  if (n >= NW) return;
  const int d = n / GP, ng = n % GP, g = ng / HP, r = ng % HP;
  dst[n] = (r < H_) ? (d ? bsb : bsf)[g*H_ + r] : 0.f;
}

// ======================= recurrent (fused; x direct-to-fragment) =========
// grid: 208 blocks = dir(2) x group(8 of 16 batches) x htile(13 of 32 cols)
// DELTA vs R13: x-path fully de-LDS'd. The MFMA A-fragment (row=lr,
// k=kk*32+lk*8..+8) is 8 contiguous bf16 at a per-lane address, so x loads
// go straight from global into A-fragments: no XS, no barrier A, no vx
// prefetch. Loads issue at step start (x first, h tag-loads second so
// waiting on x leaves h in flight); their L2-hit latency hides inside the
// exchange stall. Two 13-fragment batches cap VGPR pressure. 2 barriers
// per step. h protocol / h-MFMAs / GC / cell / publish: R13 verbatim.
template<bool LAST>
__global__ __launch_bounds__(256, 1) void lstm_rec(
    const unsigned short* __restrict__ xin,    // [T][128][832] bf16
    const unsigned short* __restrict__ wihR,   // Wih fragments
    const unsigned short* __restrict__ whhR,   // Whh fragments
    const float* __restrict__ biasp,           // [NW] f32
    const int* __restrict__ lens,
    unsigned long long* hbt,                   // tagged h (host-zeroed)
    unsigned short* __restrict__ xn,           // [T][128][832] bf16 (or unused)
    float* __restrict__ out)                   // [T][128][800] f32 (or unused)
{
  __shared__ unsigned short HS[16*424];        // 13568 B
  __shared__ float GC[4*GC_FSTRIDE];           // 9216 B

  const int tid = threadIdx.x;
  const int bid = blockIdx.x;
  const int dir  = bid / 104;
  const int rem  = bid % 104;
  const int grp  = rem / NTILES;
  const int tile = rem % NTILES;
  const int l  = tid & 63;
  const int w  = tid >> 6;
  const int lr = l & 15;
  const int lk = l >> 4;
  const int cid = dir*NGRP + grp;

  // Whh B-fragments -> 104 regs (loop-invariant)
  us8 Bf0[13], Bf1[13];
  {
    const unsigned short* bs =
        whhR + ((size_t)((dir*13 + tile)*4 + w)*2*13*64 + l)*8;
    #pragma unroll
    for (int kk = 0; kk < 13; ++kk)
      Bf0[kk] = *(const us8*)(bs + (size_t)kk*512);
    const unsigned short* bs1 = bs + (size_t)13*64*8;
    #pragma unroll
    for (int kk = 0; kk < 13; ++kk)
      Bf1[kk] = *(const us8*)(bs1 + (size_t)kk*512);
  }
  // Wih B-fragments -> 208 regs (loop-invariant)
  us8 Wf0[26], Wf1[26];
  {
    const unsigned short* ws0 =
        wihR + ((size_t)(((dir*13 + tile)*4 + w)*2 + 0)*26*64 + l)*8;
    #pragma unroll
    for (int kk = 0; kk < 26; ++kk)
      Wf0[kk] = *(const us8*)(ws0 + (size_t)kk*512);
    const unsigned short* ws1 = ws0 + (size_t)26*64*8;
    #pragma unroll
    for (int kk = 0; kk < 26; ++kk)
      Wf1[kk] = *(const us8*)(ws1 + (size_t)kk*512);
  }

  const int grp_len = lens[grp*16];          // lens sorted desc -> group max
  const int eb  = tid & 15;                  // elementwise batch
  const int p2  = tid >> 4;                  // col pair within tile
  const int mylen = lens[grp*16 + eb];
  const int c0 = 2*p2, c1 = 2*p2 + 1;
  float b0g[4], b1g[4];
  #pragma unroll
  for (int g = 0; g < 4; ++g){
    b0g[g] = biasp[dir*GP + g*HP + tile*32 + c0];
    b1g[g] = biasp[dir*GP + g*HP + tile*32 + c1];
  }
  float cs0 = 0.f, cs1 = 0.f, hs0 = 0.f, hs1 = 0.f;
  __syncthreads();

  unsigned long long* const myslot =
      hbt + (((size_t)cid*2)*16 + eb)*PAIRS + tile*16 + p2;
  // per-lane x fragment base: row = grp*16 + lr, k-offset = lk*8
  const unsigned short* const xbase = xin + ((size_t)grp*16 + lr)*KXP + lk*8;

  for (int ss = 0; ss < grp_len; ++ss){
    const int t = dir ? (grp_len - 1 - ss) : ss;
    const unsigned short* xrow = xbase + (size_t)t*B_*KXP;

    // ---- batch 1: x-frag loads kk=0..12 (issued FIRST: oldest in queue) ----
    us8 xf[13];
    #pragma unroll
    for (int kk = 0; kk < 13; ++kk)
      xf[kk] = *(const us8*)(xrow + kk*32);

    // ---- issue h tag-loads (younger; stay in flight during x-MFMAs) ----
    const unsigned rtag = (unsigned)ss;
    const unsigned long long* hb =
        hbt + ((size_t)(cid*2 + (ss & 1))*16)*PAIRS;
    unsigned long long v[13];
    #pragma unroll
    for (int j = 0; j < 13; ++j)
      v[j] = h_load_u64(hb + j*256 + tid);

    // ---- x-MFMAs batch 1 ----
    f32x4 a0 = (f32x4){0.f,0.f,0.f,0.f}, a1 = (f32x4){0.f,0.f,0.f,0.f};
    #pragma unroll
    for (int kk = 0; kk < 13; ++kk){
      a0 = __builtin_amdgcn_mfma_f32_16x16x32_bf16(xf[kk], Wf0[kk], a0, 0, 0, 0);
      a1 = __builtin_amdgcn_mfma_f32_16x16x32_bf16(xf[kk], Wf1[kk], a1, 0, 0, 0);
    }
    // ---- batch 2: x-frag loads kk=13..25 + MFMAs ----
    #pragma unroll
    for (int kk = 0; kk < 13; ++kk)
      xf[kk] = *(const us8*)(xrow + (13 + kk)*32);
    #pragma unroll
    for (int kk = 0; kk < 13; ++kk){
      a0 = __builtin_amdgcn_mfma_f32_16x16x32_bf16(xf[kk], Wf0[13 + kk], a0, 0, 0, 0);
      a1 = __builtin_amdgcn_mfma_f32_16x16x32_bf16(xf[kk], Wf1[13 + kk], a1, 0, 0, 0);
    }

    // ---- validate/retry h; write HS ----
    {
      unsigned stale = 0;
      #pragma unroll
      for (int j = 0; j < 13; ++j)
        if ((unsigned)(v[j] >> 32) != rtag) stale |= 1u << j;
      while (stale){
        const unsigned m = stale;
        #pragma unroll
        for (int j = 0; j < 13; ++j)
          if (m & (1u << j)) v[j] = h_load_u64(hb + j*256 + tid);
        #pragma unroll
        for (int j = 0; j < 13; ++j)
          if ((m & (1u << j)) && (unsigned)(v[j] >> 32) == rtag) stale &= ~(1u << j);
      }
      #pragma unroll
      for (int j = 0; j < 13; ++j){
        const int idx = j*256 + tid;
        const int b = idx / PAIRS, p = idx % PAIRS;
        *(unsigned*)&HS[b*424 + 2*p] = (unsigned)v[j];
      }
    }
    __syncthreads();                         // B: HS visible

    // ---- 26 h-side MFMAs ----
    {
      const int ab = lr*424 + lk*8;
      #pragma unroll
      for (int kk = 0; kk < 13; ++kk){
        bf16x8 av = __builtin_bit_cast(bf16x8, *(const us8*)&HS[ab + kk*32]);
        a0 = __builtin_amdgcn_mfma_f32_16x16x32_bf16(av, Bf0[kk], a0, 0, 0, 0);
        a1 = __builtin_amdgcn_mfma_f32_16x16x32_bf16(av, Bf1[kk], a1, 0, 0, 0);
      }
    }
    // ---- publish gate partials to GC ----
    {
      float* Gw = GC + w * GC_FSTRIDE;
      #pragma unroll
      for (int r = 0; r < 4; ++r){
        Gw[(lk*4 + r)*36 + lr]      = a0[r];
        Gw[(lk*4 + r)*36 + 16 + lr] = a1[r];
      }
    }
    __syncthreads();                         // C: GC visible

    // ---- elementwise LSTM cell ----
    const bool act = t < mylen;
    {
      const float gi0 = GC[0*GC_FSTRIDE + eb*36 + c0] + b0g[0];
      const float gf0 = GC[1*GC_FSTRIDE + eb*36 + c0] + b0g[1];
      const float gg0 = GC[2*GC_FSTRIDE + eb*36 + c0] + b0g[2];
      const float go0 = GC[3*GC_FSTRIDE + eb*36 + c0] + b0g[3];
      const float gi1 = GC[0*GC_FSTRIDE + eb*36 + c1] + b1g[0];
      const float gf1 = GC[1*GC_FSTRIDE + eb*36 + c1] + b1g[1];
      const float gg1 = GC[2*GC_FSTRIDE + eb*36 + c1] + b1g[2];
      const float go1 = GC[3*GC_FSTRIDE + eb*36 + c1] + b1g[3];
      const float cn0 = sigm(gf0)*cs0 + sigm(gi0)*tanh_f(gg0);
      const float hn0 = sigm(go0) * tanh_f(cn0);
      const float cn1 = sigm(gf1)*cs1 + sigm(gi1)*tanh_f(gg1);
      const float hn1 = sigm(go1) * tanh_f(cn1);
      if (act){ cs0 = cn0; hs0 = hn0; cs1 = cn1; hs1 = hn1; }
    }
    // ---- publish tagged h (frozen if masked) into next parity slot ----
    {
      const unsigned hu = (unsigned)f2bf(hs0) | ((unsigned)f2bf(hs1) << 16);
      const unsigned long long hv =
          (unsigned long long)hu | ((unsigned long long)(unsigned)(ss + 1) << 32);
      h_store_u64(myslot + ((size_t)((ss + 1) & 1))*16*PAIRS, hv);
    }
    // ---- layer outputs ----
    if (act){
      const int bg = grp*16 + eb;
      const int hc = tile*32 + c0;
      if constexpr (LAST){
        float* op = out + ((size_t)t*B_ + bg)*800 + dir*H_ + hc;
        if (hc < H_)     op[0] = hs0;
        if (hc + 1 < H_) op[1] = hs1;
      } else {
        const unsigned hu = (unsigned)f2bf(hs0) | ((unsigned)f2bf(hs1) << 16);
        *(unsigned*)(xn + ((size_t)t*B_ + bg)*KXP + (size_t)dir*HP + hc) = hu;
      }
    }
  }
}

// ======================= host side =======================
static void run_all(void* const* din, float* out, char* ws, hipStream_t stream)
{
  const float* x      = (const float*)din[0];
  const int* lens     = (const int*)din[1];
  const float* wihf0  = (const float*)din[2];
  const float* wihf12 = (const float*)din[3];
  const float* whhf   = (const float*)din[4];
  const float* bsf    = (const float*)din[5];
  const float* wihb0  = (const float*)din[6];
  const float* wihb12 = (const float*)din[7];
  const float* whhb   = (const float*)din[8];
  const float* bsb    = (const float*)din[9];

  char* p = ws;
  auto alloc = [&](size_t n){ char* r = p; p += (n + 255) & ~(size_t)255; return r; };
  unsigned short* xA = (unsigned short*)alloc((size_t)T_*B_*KXP*2);
  unsigned short* xB = (unsigned short*)alloc((size_t)T_*B_*KXP*2);
  unsigned short* wihR = (unsigned short*)alloc(WIHR_BYTES);
  unsigned short* whhR = (unsigned short*)alloc(WHHR_BYTES);
  float* biasp       = (float*)alloc((size_t)NW*4);
  unsigned long long* hbt = (unsigned long long*)alloc(HBT_BYTES);

  hipMemsetAsync(out, 0, (size_t)T_*B_*800*4, stream);
  {
    size_t n = (size_t)T_*B_*KXP;
    k_conv_x0<<<dim3((unsigned)((n+255)/256)), dim3(256), 0, stream>>>(x, xA);
  }

  const unsigned short* xinv[3] = {xA, xB, xA};
  unsigned short* xoutv[3] = {xB, xA, nullptr};

  for (int lyr = 0; lyr < 3; ++lyr){
    const float* wf = (lyr == 0) ? wihf0 : wihf12 + (size_t)(lyr-1)*1600*800;
    const float* wb = (lyr == 0) ? wihb0 : wihb12 + (size_t)(lyr-1)*1600*800;
    {
      size_t n = WIHR_US8;
      k_prep_wihR<<<dim3((unsigned)((n+255)/256)), dim3(256), 0, stream>>>(
          wf, wb, lyr ? 1 : 0, wihR);
    }
    k_prep_bias<<<dim3((NW+255)/256), dim3(256), 0, stream>>>(
        bsf + (size_t)lyr*1600, bsb + (size_t)lyr*1600, biasp);
    {
      size_t n = WHHR_US8;
      k_prep_whhR<<<dim3((unsigned)((n+255)/256)), dim3(256), 0, stream>>>(
          whhf + (size_t)lyr*1600*400, whhb + (size_t)lyr*1600*400, whhR);
    }
    hipMemsetAsync(hbt, 0, HBT_BYTES, stream);

    if (lyr < 2)
      lstm_rec<false><<<dim3(REC_BLOCKS), dim3(256), 0, stream>>>(
          xinv[lyr], wihR, whhR, biasp, lens, hbt, xoutv[lyr], out);
    else
      lstm_rec<true><<<dim3(REC_BLOCKS), dim3(256), 0, stream>>>(
          xinv[lyr], wihR, whhR, biasp, lens, hbt, nullptr, out);
  }
}

extern "C" void kernel_launch(void* const* d_in, const int* in_sizes, int n_in,
                              void* d_out, int out_size, void* d_ws, size_t ws_size,
                              hipStream_t stream)
{
  (void)in_sizes; (void)n_in; (void)out_size;
  auto align = [](size_t n){ return (n + 255) & ~(size_t)255; };
  const size_t need =
      align((size_t)T_*B_*KXP*2) * 2 +
      align(WIHR_BYTES) +
      align(WHHR_BYTES) +
      align((size_t)NW*4) +
      align(HBT_BYTES);

  if (ws_size >= need)
    run_all(d_in, (float*)d_out, (char*)d_ws, stream);
  else
    hipMemsetAsync(d_out, 0, (size_t)T_*B_*800*4, stream);
}

// Round 15
// 8731.779 us; speedup vs baseline: 1.2494x; 1.2494x over previous
//
#include <hip/hip_runtime.h>
#include <stdint.h>
#include <stddef.h>

#define T_ 512
#define B_ 128
#define D_ 400
#define H_ 400
#define HP 416
#define GP 1664            // 4*HP (per-dir padded gate dim)
#define NW 3328            // both dirs stacked
#define KXP 832            // uniform padded x-K for all layers
#define NTILES 13          // h tiles of 32 per dir
#define NGRP 8             // batch groups of 16
#define REC_BLOCKS 208     // 2*8*13
#define PAIRS 208          // 416 cols / 2 per batch row (u64 slots)

// GC: stride 37 words (bank-conflict fix; was 36)
#define GC_W 37
#define GC_FSTRIDE (16*GC_W)                 // 592 floats per gate region

// rec LDS layout (dynamic): HS | XS[2] | GC
#define HS_BYTES  (16*424*2)                 // 13568
#define XS_STRIDE 840
#define XS_BYTES  (16*XS_STRIDE*2)           // 26880
#define XS0_OFF   HS_BYTES
#define XS1_OFF   (HS_BYTES + XS_BYTES)
#define GC_OFF    (HS_BYTES + 2*XS_BYTES)    // 67328
#define LDS_TOTAL (GC_OFF + 4*GC_FSTRIDE*4)  // 76800

// tagged h buffer: [16 cid][2 parity][16 batch][208 pair] u64
#define HBT_U64   ((size_t)16*2*16*PAIRS)
#define HBT_BYTES (HBT_U64*8)

// Whh register-fragment blob: [2 dir][13 tile][4 gate][2 ch][13 kk][64 lane][8]
#define WHHR_US8  ((size_t)2*13*4*2*13*64)
#define WHHR_BYTES (WHHR_US8*8*2)
// Wih register-fragment blob: [2 dir][13 tile][4 gate][2 ch][26 kk][64 lane][8]
#define WIHR_US8  ((size_t)2*13*4*2*26*64)
#define WIHR_BYTES (WIHR_US8*8*2)

typedef __attribute__((ext_vector_type(8))) __bf16 bf16x8;
typedef __attribute__((ext_vector_type(4))) float f32x4;
typedef __attribute__((ext_vector_type(8))) unsigned short us8;

__device__ __forceinline__ unsigned short f2bf(float f){
  unsigned u = __builtin_bit_cast(unsigned, f);
  u = (u + 0x7FFFu + ((u >> 16) & 1u)) >> 16;
  return (unsigned short)u;
}
__device__ __forceinline__ float bf2f(unsigned short s){
  unsigned u = ((unsigned)s) << 16;
  return __builtin_bit_cast(float, u);
}
__device__ __forceinline__ float sigm(float x){ return 1.f / (1.f + __expf(-x)); }
__device__ __forceinline__ float tanh_f(float x){
  float ax = fabsf(x);
  float e = __expf(-2.f * ax);
  float t = (1.f - e) / (1.f + e);
  return x < 0.f ? -t : t;
}

// agent-scope relaxed atomics == MALL-coherent accesses, NO cache maintenance
__device__ __forceinline__ void h_store_u64(unsigned long long* p, unsigned long long v){
  __hip_atomic_store(p, v, __ATOMIC_RELAXED, __HIP_MEMORY_SCOPE_AGENT);
}
__device__ __forceinline__ unsigned long long h_load_u64(const unsigned long long* p){
  return __hip_atomic_load(p, __ATOMIC_RELAXED, __HIP_MEMORY_SCOPE_AGENT);
}

// ======================= prep kernels =======================
__global__ void k_conv_x0(const float* __restrict__ x, unsigned short* __restrict__ xa){
  const size_t i = (size_t)blockIdx.x*256 + threadIdx.x;
  if (i >= (size_t)T_*B_*KXP) return;
  const int k = (int)(i % KXP);
  const size_t tb = i / KXP;
  xa[i] = f2bf(k < D_ ? x[tb*D_ + k] : 0.f);
}

// Wih -> MFMA B-fragments [2 dir][13 tile][4 gate][2 ch][26 kk][64 lane][8]
__global__ void k_prep_wihR(const float* __restrict__ wf, const float* __restrict__ wb,
                            int mode, unsigned short* __restrict__ dst){
  const size_t i = (size_t)blockIdx.x*256 + threadIdx.x;
  if (i >= WIHR_US8) return;
  const int lane = (int)(i & 63);
  size_t q = i >> 6;
  const int kk = (int)(q % 26); q /= 26;
  const int ch = (int)(q % 2);  q /= 2;
  const int g  = (int)(q % 4);  q /= 4;
  const int tile = (int)(q % 13);
  const int dirx = (int)(q / 13);
  const int c  = tile*32 + ch*16 + (lane & 15);
  const int k0 = kk*32 + (lane >> 4)*8;
  const float* W = dirx ? wb : wf;
  const int stride = mode ? 800 : D_;
  unsigned short v[8];
  #pragma unroll
  for (int e = 0; e < 8; ++e){
    const int k = k0 + e;
    int ks;
    if (mode == 0) ks = (k < D_) ? k : -1;
    else           ks = (k < 400) ? k : ((k >= 416 && k < 816) ? (k - 16) : -1);
    const float x = (c < H_ && ks >= 0) ? W[(size_t)(g*H_ + c)*stride + ks] : 0.f;
    v[e] = f2bf(x);
  }
  *(us8*)(dst + i*8) = *(const us8*)v;
}

// Whh -> B-fragments (R7-verified layout)
__global__ void k_prep_whhR(const float* __restrict__ wf, const float* __restrict__ wb,
                            unsigned short* __restrict__ dst){
  const size_t i = (size_t)blockIdx.x*256 + threadIdx.x;
  if (i >= WHHR_US8) return;
  const int lane = (int)(i & 63);
  size_t q = i >> 6;
  const int kk = (int)(q % 13); q /= 13;
  const int ch = (int)(q % 2);  q /= 2;
  const int w  = (int)(q % 4);  q /= 4;
  const int tile = (int)(q % 13);
  const int dirx = (int)(q / 13);
  const int c  = tile*32 + ch*16 + (lane & 15);
  const int k0 = kk*32 + (lane >> 4)*8;
  const float* W = dirx ? wb : wf;
  unsigned short v[8];
  #pragma unroll
  for (int e = 0; e < 8; ++e){
    const int k = k0 + e;
    const float x = (c < H_ && k < H_) ? W[(size_t)(w*H_ + c)*H_ + k] : 0.f;
    v[e] = f2bf(x);
  }
  *(us8*)(dst + i*8) = *(const us8*)v;
}

__global__ void k_prep_bias(const float* __restrict__ bsf, const float* __restrict__ bsb,
                            float* __restrict__ dst){
  const int n = blockIdx.x*256 + threadIdx.x;
  if (n >= NW) return;
  const int d = n / GP, ng = n % GP, g = ng / HP, r = ng % HP;
  dst[n] = (r < H_) ? (d ? bsb : bsf)[g*H_ + r] : 0.f;
}

// ======================= recurrent (R13 + swizzle + double-sample) =======
// grid: 208 blocks = dir(2) x group(8 of 16 batches) x htile(13 of 32 cols)
// Base = R13 (proven 5120us). Deltas:
//  1) XS XOR-swizzle: in-row short-offset ^= (row&7)<<3 on write AND read
//     (R13's XS read was ~8-way bank-conflicted; both-sides-same-involution)
//  2) GC stride 36->37 words (cell's scalar reads were ~4-way conflicted)
//  3) speculative double-sample of h: second unconditional sample issued
//     between the two x-MFMA batches; stale v1 lines take v2 before any
//     retry -> removes one MALL RT from the common stale case.
template<bool LAST>
__global__ __launch_bounds__(256, 1) void lstm_rec(
    const unsigned short* __restrict__ xin,    // [T][128][832] bf16
    const unsigned short* __restrict__ wihR,   // Wih fragments
    const unsigned short* __restrict__ whhR,   // Whh fragments
    const float* __restrict__ biasp,           // [NW] f32
    const int* __restrict__ lens,
    unsigned long long* hbt,                   // tagged h (host-zeroed)
    unsigned short* __restrict__ xn,           // [T][128][832] bf16 (or unused)
    float* __restrict__ out)                   // [T][128][800] f32 (or unused)
{
  extern __shared__ char smem[];
  unsigned short* HS = (unsigned short*)smem;                // [16][424]
  unsigned short* XS0 = (unsigned short*)(smem + XS0_OFF);   // [16][840] swz
  unsigned short* XS1 = (unsigned short*)(smem + XS1_OFF);   // [16][840] swz
  float* GC = (float*)(smem + GC_OFF);                       // [4][592]

  const int tid = threadIdx.x;
  const int bid = blockIdx.x;
  const int dir  = bid / 104;
  const int rem  = bid % 104;
  const int grp  = rem / NTILES;
  const int tile = rem % NTILES;
  const int l  = tid & 63;
  const int w  = tid >> 6;
  const int lr = l & 15;
  const int lk = l >> 4;
  const int cid = dir*NGRP + grp;

  // Whh B-fragments -> 104 regs (loop-invariant)
  us8 Bf0[13], Bf1[13];
  {
    const unsigned short* bs =
        whhR + ((size_t)((dir*13 + tile)*4 + w)*2*13*64 + l)*8;
    #pragma unroll
    for (int kk = 0; kk < 13; ++kk)
      Bf0[kk] = *(const us8*)(bs + (size_t)kk*512);
    const unsigned short* bs1 = bs + (size_t)13*64*8;
    #pragma unroll
    for (int kk = 0; kk < 13; ++kk)
      Bf1[kk] = *(const us8*)(bs1 + (size_t)kk*512);
  }
  // Wih B-fragments -> 208 regs (loop-invariant)
  us8 Wf0[26], Wf1[26];
  {
    const unsigned short* ws0 =
        wihR + ((size_t)(((dir*13 + tile)*4 + w)*2 + 0)*26*64 + l)*8;
    #pragma unroll
    for (int kk = 0; kk < 26; ++kk)
      Wf0[kk] = *(const us8*)(ws0 + (size_t)kk*512);
    const unsigned short* ws1 = ws0 + (size_t)26*64*8;
    #pragma unroll
    for (int kk = 0; kk < 26; ++kk)
      Wf1[kk] = *(const us8*)(ws1 + (size_t)kk*512);
  }

  const int grp_len = lens[grp*16];          // lens sorted desc -> group max
  const int eb  = tid & 15;                  // elementwise batch
  const int p2  = tid >> 4;                  // col pair within tile
  const int mylen = lens[grp*16 + eb];
  const int c0 = 2*p2, c1 = 2*p2 + 1;
  float b0g[4], b1g[4];
  #pragma unroll
  for (int g = 0; g < 4; ++g){
    b0g[g] = biasp[dir*GP + g*HP + tile*32 + c0];
    b1g[g] = biasp[dir*GP + g*HP + tile*32 + c1];
  }
  float cs0 = 0.f, cs1 = 0.f, hs0 = 0.f, hs1 = 0.f;
  __syncthreads();

  unsigned long long* const myslot =
      hbt + (((size_t)cid*2)*16 + eb)*PAIRS + tile*16 + p2;

  // ---- prologue: load vx for step 0 ----
  unsigned long long vx[13];
  {
    const int t0 = dir ? (grp_len - 1) : 0;
    const unsigned long long* xrow =
        (const unsigned long long*)(xin + ((size_t)t0*B_ + grp*16)*KXP);
    #pragma unroll
    for (int j = 0; j < 13; ++j){
      const int idx = j*256 + tid;
      const int b = idx / 208, qq = idx % 208;
      vx[j] = xrow[(size_t)b*208 + qq];
    }
  }

  for (int ss = 0; ss < grp_len; ++ss){
    const int t = dir ? (grp_len - 1 - ss) : ss;
    unsigned short* XSb = (ss & 1) ? XS1 : XS0;

    // ---- write XS[par] from prefetched vx (XOR-swizzled) ----
    #pragma unroll
    for (int j = 0; j < 13; ++j){
      const int idx = j*256 + tid;
      const int b = idx / 208, qq = idx % 208;
      *(unsigned long long*)&XSb[b*XS_STRIDE + ((qq*4) ^ ((b & 7) << 3))] = vx[j];
    }
    // ---- prefetch vx for step ss+1 (flies across the whole step) ----
    if (ss + 1 < grp_len){
      const int tn = dir ? (grp_len - 2 - ss) : (ss + 1);
      const unsigned long long* xrow =
          (const unsigned long long*)(xin + ((size_t)tn*B_ + grp*16)*KXP);
      #pragma unroll
      for (int j = 0; j < 13; ++j){
        const int idx = j*256 + tid;
        const int b = idx / 208, qq = idx % 208;
        vx[j] = xrow[(size_t)b*208 + qq];
      }
    }
    __syncthreads();                         // A: XS[par] visible

    // ---- issue h tag-loads, sample 1 (in flight during x-MFMAs) ----
    const unsigned rtag = (unsigned)ss;
    const unsigned long long* hb =
        hbt + ((size_t)(cid*2 + (ss & 1))*16)*PAIRS;
    unsigned long long v[13];
    #pragma unroll
    for (int j = 0; j < 13; ++j)
      v[j] = h_load_u64(hb + j*256 + tid);

    // ---- x-MFMAs batch 1 (kk 0..12) ----
    f32x4 a0 = (f32x4){0.f,0.f,0.f,0.f}, a1 = (f32x4){0.f,0.f,0.f,0.f};
    const int xsz = (lr & 7) << 3;
    {
      const int abx = lr*XS_STRIDE;
      #pragma unroll
      for (int kk = 0; kk < 13; ++kk){
        bf16x8 xa = __builtin_bit_cast(bf16x8,
            *(const us8*)&XSb[abx + ((lk*8 + kk*32) ^ xsz)]);
        a0 = __builtin_amdgcn_mfma_f32_16x16x32_bf16(xa, Wf0[kk], a0, 0, 0, 0);
        a1 = __builtin_amdgcn_mfma_f32_16x16x32_bf16(xa, Wf1[kk], a1, 0, 0, 0);
      }
    }
    // ---- speculative sample 2 (unconditional; fresher than sample 1) ----
    unsigned long long v2[13];
    #pragma unroll
    for (int j = 0; j < 13; ++j)
      v2[j] = h_load_u64(hb + j*256 + tid);

    // ---- x-MFMAs batch 2 (kk 13..25) ----
    {
      const int abx = lr*XS_STRIDE;
      #pragma unroll
      for (int kk = 13; kk < 26; ++kk){
        bf16x8 xa = __builtin_bit_cast(bf16x8,
            *(const us8*)&XSb[abx + ((lk*8 + kk*32) ^ xsz)]);
        a0 = __builtin_amdgcn_mfma_f32_16x16x32_bf16(xa, Wf0[kk], a0, 0, 0, 0);
        a1 = __builtin_amdgcn_mfma_f32_16x16x32_bf16(xa, Wf1[kk], a1, 0, 0, 0);
      }
    }

    // ---- validate: v1, fall back to v2, then retry loop ----
    {
      unsigned stale = 0;
      #pragma unroll
      for (int j = 0; j < 13; ++j)
        if ((unsigned)(v[j] >> 32) != rtag) stale |= 1u << j;
      if (stale){
        #pragma unroll
        for (int j = 0; j < 13; ++j)
          if (stale & (1u << j)) v[j] = v2[j];
        #pragma unroll
        for (int j = 0; j < 13; ++j)
          if ((stale & (1u << j)) && (unsigned)(v[j] >> 32) == rtag) stale &= ~(1u << j);
      }
      while (stale){
        const unsigned m = stale;
        #pragma unroll
        for (int j = 0; j < 13; ++j)
          if (m & (1u << j)) v[j] = h_load_u64(hb + j*256 + tid);
        #pragma unroll
        for (int j = 0; j < 13; ++j)
          if ((m & (1u << j)) && (unsigned)(v[j] >> 32) == rtag) stale &= ~(1u << j);
      }
      #pragma unroll
      for (int j = 0; j < 13; ++j){
        const int idx = j*256 + tid;
        const int b = idx / PAIRS, p = idx % PAIRS;
        *(unsigned*)&HS[b*424 + 2*p] = (unsigned)v[j];
      }
    }
    __syncthreads();                         // B: HS visible

    // ---- 26 h-side MFMAs ----
    {
      const int ab = lr*424 + lk*8;
      #pragma unroll
      for (int kk = 0; kk < 13; ++kk){
        bf16x8 av = __builtin_bit_cast(bf16x8, *(const us8*)&HS[ab + kk*32]);
        a0 = __builtin_amdgcn_mfma_f32_16x16x32_bf16(av, Bf0[kk], a0, 0, 0, 0);
        a1 = __builtin_amdgcn_mfma_f32_16x16x32_bf16(av, Bf1[kk], a1, 0, 0, 0);
      }
    }
    // ---- publish gate partials to GC (stride GC_W) ----
    {
      float* Gw = GC + w * GC_FSTRIDE;
      #pragma unroll
      for (int r = 0; r < 4; ++r){
        Gw[(lk*4 + r)*GC_W + lr]      = a0[r];
        Gw[(lk*4 + r)*GC_W + 16 + lr] = a1[r];
      }
    }
    __syncthreads();                         // C: GC visible

    // ---- elementwise LSTM cell ----
    const bool act = t < mylen;
    {
      const float gi0 = GC[0*GC_FSTRIDE + eb*GC_W + c0] + b0g[0];
      const float gf0 = GC[1*GC_FSTRIDE + eb*GC_W + c0] + b0g[1];
      const float gg0 = GC[2*GC_FSTRIDE + eb*GC_W + c0] + b0g[2];
      const float go0 = GC[3*GC_FSTRIDE + eb*GC_W + c0] + b0g[3];
      const float gi1 = GC[0*GC_FSTRIDE + eb*GC_W + c1] + b1g[0];
      const float gf1 = GC[1*GC_FSTRIDE + eb*GC_W + c1] + b1g[1];
      const float gg1 = GC[2*GC_FSTRIDE + eb*GC_W + c1] + b1g[2];
      const float go1 = GC[3*GC_FSTRIDE + eb*GC_W + c1] + b1g[3];
      const float cn0 = sigm(gf0)*cs0 + sigm(gi0)*tanh_f(gg0);
      const float hn0 = sigm(go0) * tanh_f(cn0);
      const float cn1 = sigm(gf1)*cs1 + sigm(gi1)*tanh_f(gg1);
      const float hn1 = sigm(go1) * tanh_f(cn1);
      if (act){ cs0 = cn0; hs0 = hn0; cs1 = cn1; hs1 = hn1; }
    }
    // ---- publish tagged h (frozen if masked) into next parity slot ----
    {
      const unsigned hu = (unsigned)f2bf(hs0) | ((unsigned)f2bf(hs1) << 16);
      const unsigned long long hv =
          (unsigned long long)hu | ((unsigned long long)(unsigned)(ss + 1) << 32);
      h_store_u64(myslot + ((size_t)((ss + 1) & 1))*16*PAIRS, hv);
    }
    // ---- layer outputs ----
    if (act){
      const int bg = grp*16 + eb;
      const int hc = tile*32 + c0;
      if constexpr (LAST){
        float* op = out + ((size_t)t*B_ + bg)*800 + dir*H_ + hc;
        if (hc < H_)     op[0] = hs0;
        if (hc + 1 < H_) op[1] = hs1;
      } else {
        const unsigned hu = (unsigned)f2bf(hs0) | ((unsigned)f2bf(hs1) << 16);
        *(unsigned*)(xn + ((size_t)t*B_ + bg)*KXP + (size_t)dir*HP + hc) = hu;
      }
    }
  }
}

// ======================= host side =======================
static void run_all(void* const* din, float* out, char* ws, hipStream_t stream)
{
  const float* x      = (const float*)din[0];
  const int* lens     = (const int*)din[1];
  const float* wihf0  = (const float*)din[2];
  const float* wihf12 = (const float*)din[3];
  const float* whhf   = (const float*)din[4];
  const float* bsf    = (const float*)din[5];
  const float* wihb0  = (const float*)din[6];
  const float* wihb12 = (const float*)din[7];
  const float* whhb   = (const float*)din[8];
  const float* bsb    = (const float*)din[9];

  char* p = ws;
  auto alloc = [&](size_t n){ char* r = p; p += (n + 255) & ~(size_t)255; return r; };
  unsigned short* xA = (unsigned short*)alloc((size_t)T_*B_*KXP*2);
  unsigned short* xB = (unsigned short*)alloc((size_t)T_*B_*KXP*2);
  unsigned short* wihR = (unsigned short*)alloc(WIHR_BYTES);
  unsigned short* whhR = (unsigned short*)alloc(WHHR_BYTES);
  float* biasp       = (float*)alloc((size_t)NW*4);
  unsigned long long* hbt = (unsigned long long*)alloc(HBT_BYTES);

  hipMemsetAsync(out, 0, (size_t)T_*B_*800*4, stream);
  {
    size_t n = (size_t)T_*B_*KXP;
    k_conv_x0<<<dim3((unsigned)((n+255)/256)), dim3(256), 0, stream>>>(x, xA);
  }
  hipFuncSetAttribute(reinterpret_cast<const void*>(&lstm_rec<false>),
                      hipFuncAttributeMaxDynamicSharedMemorySize, LDS_TOTAL);
  hipFuncSetAttribute(reinterpret_cast<const void*>(&lstm_rec<true>),
                      hipFuncAttributeMaxDynamicSharedMemorySize, LDS_TOTAL);

  const unsigned short* xinv[3] = {xA, xB, xA};
  unsigned short* xoutv[3] = {xB, xA, nullptr};

  for (int lyr = 0; lyr < 3; ++lyr){
    const float* wf = (lyr == 0) ? wihf0 : wihf12 + (size_t)(lyr-1)*1600*800;
    const float* wb = (lyr == 0) ? wihb0 : wihb12 + (size_t)(lyr-1)*1600*800;
    {
      size_t n = WIHR_US8;
      k_prep_wihR<<<dim3((unsigned)((n+255)/256)), dim3(256), 0, stream>>>(
          wf, wb, lyr ? 1 : 0, wihR);
    }
    k_prep_bias<<<dim3((NW+255)/256), dim3(256), 0, stream>>>(
        bsf + (size_t)lyr*1600, bsb + (size_t)lyr*1600, biasp);
    {
      size_t n = WHHR_US8;
      k_prep_whhR<<<dim3((unsigned)((n+255)/256)), dim3(256), 0, stream>>>(
          whhf + (size_t)lyr*1600*400, whhb + (size_t)lyr*1600*400, whhR);
    }
    hipMemsetAsync(hbt, 0, HBT_BYTES, stream);

    if (lyr < 2)
      lstm_rec<false><<<dim3(REC_BLOCKS), dim3(256), LDS_TOTAL, stream>>>(
          xinv[lyr], wihR, whhR, biasp, lens, hbt, xoutv[lyr], out);
    else
      lstm_rec<true><<<dim3(REC_BLOCKS), dim3(256), LDS_TOTAL, stream>>>(
          xinv[lyr], wihR, whhR, biasp, lens, hbt, nullptr, out);
  }
}

extern "C" void kernel_launch(void* const* d_in, const int* in_sizes, int n_in,
                              void* d_out, int out_size, void* d_ws, size_t ws_size,
                              hipStream_t stream)
{
  (void)in_sizes; (void)n_in; (void)out_size;
  auto align = [](size_t n){ return (n + 255) & ~(size_t)255; };
  const size_t need =
      align((size_t)T_*B_*KXP*2) * 2 +
      align(WIHR_BYTES) +
      align(WHHR_BYTES) +
      align((size_t)NW*4) +
      align(HBT_BYTES);

  if (ws_size >= need)
    run_all(d_in, (float*)d_out, (char*)d_ws, stream);
  else
    hipMemsetAsync(d_out, 0, (size_t)T_*B_*800*4, stream);
}

// Round 16
// 6315.572 us; speedup vs baseline: 1.7274x; 1.3826x over previous
//
#include <hip/hip_runtime.h>
#include <stdint.h>
#include <stddef.h>

#define T_ 512
#define B_ 128
#define D_ 400
#define H_ 400
#define HP 416
#define GP 1664            // 4*HP (per-dir padded gate dim)
#define NW 3328            // both dirs stacked
#define KXP 832            // uniform padded x-K for all layers
#define NTILES 13          // h tiles of 32 per dir
#define NGRP 8             // batch groups of 16
#define REC_BLOCKS 208     // 2*8*13
#define PAIRS 208          // 416 cols / 2 per batch row (u64 slots)

// GC float stride (R13 layout)
#define GC_FSTRIDE 576     // 16*36

// rec LDS layout (dynamic): HS | XS[2] | GC
#define HS_BYTES  (16*424*2)                 // 13568
#define XS_STRIDE 840
#define XS_BYTES  (16*XS_STRIDE*2)           // 26880
#define XS0_OFF   HS_BYTES
#define XS1_OFF   (HS_BYTES + XS_BYTES)
#define GC_OFF    (HS_BYTES + 2*XS_BYTES)    // 67328
#define LDS_TOTAL (GC_OFF + 4*GC_FSTRIDE*4)  // 76544

// tagged h buffer: [16 cid][2 parity][16 batch][208 pair] u64
#define HBT_U64   ((size_t)16*2*16*PAIRS)
#define HBT_BYTES (HBT_U64*8)

// Whh register-fragment blob: [2 dir][13 tile][4 gate][2 ch][13 kk][64 lane][8]
#define WHHR_US8  ((size_t)2*13*4*2*13*64)
#define WHHR_BYTES (WHHR_US8*8*2)
// Wih register-fragment blob: [2 dir][13 tile][4 gate][2 ch][26 kk][64 lane][8]
#define WIHR_US8  ((size_t)2*13*4*2*26*64)
#define WIHR_BYTES (WIHR_US8*8*2)

typedef __attribute__((ext_vector_type(8))) __bf16 bf16x8;
typedef __attribute__((ext_vector_type(4))) float f32x4;
typedef __attribute__((ext_vector_type(8))) unsigned short us8;

__device__ __forceinline__ unsigned short f2bf(float f){
  unsigned u = __builtin_bit_cast(unsigned, f);
  u = (u + 0x7FFFu + ((u >> 16) & 1u)) >> 16;
  return (unsigned short)u;
}
__device__ __forceinline__ float bf2f(unsigned short s){
  unsigned u = ((unsigned)s) << 16;
  return __builtin_bit_cast(float, u);
}
__device__ __forceinline__ float sigm(float x){ return 1.f / (1.f + __expf(-x)); }
__device__ __forceinline__ float tanh_f(float x){
  float ax = fabsf(x);
  float e = __expf(-2.f * ax);
  float t = (1.f - e) / (1.f + e);
  return x < 0.f ? -t : t;
}

// agent-scope relaxed atomics == MALL-coherent accesses, NO cache maintenance
__device__ __forceinline__ void h_store_u64(unsigned long long* p, unsigned long long v){
  __hip_atomic_store(p, v, __ATOMIC_RELAXED, __HIP_MEMORY_SCOPE_AGENT);
}
__device__ __forceinline__ unsigned long long h_load_u64(const unsigned long long* p){
  return __hip_atomic_load(p, __ATOMIC_RELAXED, __HIP_MEMORY_SCOPE_AGENT);
}

// ======================= prep kernels =======================
__global__ void k_conv_x0(const float* __restrict__ x, unsigned short* __restrict__ xa){
  const size_t i = (size_t)blockIdx.x*256 + threadIdx.x;
  if (i >= (size_t)T_*B_*KXP) return;
  const int k = (int)(i % KXP);
  const size_t tb = i / KXP;
  xa[i] = f2bf(k < D_ ? x[tb*D_ + k] : 0.f);
}

// Wih -> MFMA B-fragments [2 dir][13 tile][4 gate][2 ch][26 kk][64 lane][8]
__global__ void k_prep_wihR(const float* __restrict__ wf, const float* __restrict__ wb,
                            int mode, unsigned short* __restrict__ dst){
  const size_t i = (size_t)blockIdx.x*256 + threadIdx.x;
  if (i >= WIHR_US8) return;
  const int lane = (int)(i & 63);
  size_t q = i >> 6;
  const int kk = (int)(q % 26); q /= 26;
  const int ch = (int)(q % 2);  q /= 2;
  const int g  = (int)(q % 4);  q /= 4;
  const int tile = (int)(q % 13);
  const int dirx = (int)(q / 13);
  const int c  = tile*32 + ch*16 + (lane & 15);
  const int k0 = kk*32 + (lane >> 4)*8;
  const float* W = dirx ? wb : wf;
  const int stride = mode ? 800 : D_;
  unsigned short v[8];
  #pragma unroll
  for (int e = 0; e < 8; ++e){
    const int k = k0 + e;
    int ks;
    if (mode == 0) ks = (k < D_) ? k : -1;
    else           ks = (k < 400) ? k : ((k >= 416 && k < 816) ? (k - 16) : -1);
    const float x = (c < H_ && ks >= 0) ? W[(size_t)(g*H_ + c)*stride + ks] : 0.f;
    v[e] = f2bf(x);
  }
  *(us8*)(dst + i*8) = *(const us8*)v;
}

// Whh -> B-fragments (R7-verified layout)
__global__ void k_prep_whhR(const float* __restrict__ wf, const float* __restrict__ wb,
                            unsigned short* __restrict__ dst){
  const size_t i = (size_t)blockIdx.x*256 + threadIdx.x;
  if (i >= WHHR_US8) return;
  const int lane = (int)(i & 63);
  size_t q = i >> 6;
  const int kk = (int)(q % 13); q /= 13;
  const int ch = (int)(q % 2);  q /= 2;
  const int w  = (int)(q % 4);  q /= 4;
  const int tile = (int)(q % 13);
  const int dirx = (int)(q / 13);
  const int c  = tile*32 + ch*16 + (lane & 15);
  const int k0 = kk*32 + (lane >> 4)*8;
  const float* W = dirx ? wb : wf;
  unsigned short v[8];
  #pragma unroll
  for (int e = 0; e < 8; ++e){
    const int k = k0 + e;
    const float x = (c < H_ && k < H_) ? W[(size_t)(w*H_ + c)*H_ + k] : 0.f;
    v[e] = f2bf(x);
  }
  *(us8*)(dst + i*8) = *(const us8*)v;
}

__global__ void k_prep_bias(const float* __restrict__ bsf, const float* __restrict__ bsb,
                            float* __restrict__ dst){
  const int n = blockIdx.x*256 + threadIdx.x;
  if (n >= NW) return;
  const int d = n / GP, ng = n % GP, g = ng / HP, r = ng % HP;
  dst[n] = (r < H_) ? (d ? bsb : bsf)[g*H_ + r] : 0.f;
}

// ======================= recurrent (R13 schedule, 2 barriers/step) =======
// grid: 208 blocks = dir(2) x group(8 of 16 batches) x htile(13 of 32 cols)
// Base = R13 (proven 5120us). Single delta: barrier A removed. New order:
//   [h tag-loads] -> [26 x-MFMAs read XS[par]] -> [write XS[par^1] from
//   prefetched vx] -> [prefetch vx for ss+2] -> [validate/retry h; HS] ->
//   barrier B -> [h-MFMAs; GC] -> barrier C -> [cell; publish; outputs]
// Hazards: XS[par^1] write(ss) vs reads(ss+1): separated by B(ss) [write
// before B, reads after]. vs reads(ss-1): those end before B(ss-1), write
// is after C(ss-1). HS/GC hazards unchanged from R13. VGPR-neutral.
template<bool LAST>
__global__ __launch_bounds__(256, 1) void lstm_rec(
    const unsigned short* __restrict__ xin,    // [T][128][832] bf16
    const unsigned short* __restrict__ wihR,   // Wih fragments
    const unsigned short* __restrict__ whhR,   // Whh fragments
    const float* __restrict__ biasp,           // [NW] f32
    const int* __restrict__ lens,
    unsigned long long* hbt,                   // tagged h (host-zeroed)
    unsigned short* __restrict__ xn,           // [T][128][832] bf16 (or unused)
    float* __restrict__ out)                   // [T][128][800] f32 (or unused)
{
  extern __shared__ char smem[];
  unsigned short* HS = (unsigned short*)smem;                // [16][424]
  unsigned short* XS0 = (unsigned short*)(smem + XS0_OFF);   // [16][840]
  unsigned short* XS1 = (unsigned short*)(smem + XS1_OFF);   // [16][840]
  float* GC = (float*)(smem + GC_OFF);                       // [4][576]

  const int tid = threadIdx.x;
  const int bid = blockIdx.x;
  const int dir  = bid / 104;
  const int rem  = bid % 104;
  const int grp  = rem / NTILES;
  const int tile = rem % NTILES;
  const int l  = tid & 63;
  const int w  = tid >> 6;
  const int lr = l & 15;
  const int lk = l >> 4;
  const int cid = dir*NGRP + grp;

  // Whh B-fragments -> 104 regs (loop-invariant)
  us8 Bf0[13], Bf1[13];
  {
    const unsigned short* bs =
        whhR + ((size_t)((dir*13 + tile)*4 + w)*2*13*64 + l)*8;
    #pragma unroll
    for (int kk = 0; kk < 13; ++kk)
      Bf0[kk] = *(const us8*)(bs + (size_t)kk*512);
    const unsigned short* bs1 = bs + (size_t)13*64*8;
    #pragma unroll
    for (int kk = 0; kk < 13; ++kk)
      Bf1[kk] = *(const us8*)(bs1 + (size_t)kk*512);
  }
  // Wih B-fragments -> 208 regs (loop-invariant)
  us8 Wf0[26], Wf1[26];
  {
    const unsigned short* ws0 =
        wihR + ((size_t)(((dir*13 + tile)*4 + w)*2 + 0)*26*64 + l)*8;
    #pragma unroll
    for (int kk = 0; kk < 26; ++kk)
      Wf0[kk] = *(const us8*)(ws0 + (size_t)kk*512);
    const unsigned short* ws1 = ws0 + (size_t)26*64*8;
    #pragma unroll
    for (int kk = 0; kk < 26; ++kk)
      Wf1[kk] = *(const us8*)(ws1 + (size_t)kk*512);
  }

  const int grp_len = lens[grp*16];          // lens sorted desc -> group max
  const int eb  = tid & 15;                  // elementwise batch
  const int p2  = tid >> 4;                  // col pair within tile
  const int mylen = lens[grp*16 + eb];
  const int c0 = 2*p2, c1 = 2*p2 + 1;
  float b0g[4], b1g[4];
  #pragma unroll
  for (int g = 0; g < 4; ++g){
    b0g[g] = biasp[dir*GP + g*HP + tile*32 + c0];
    b1g[g] = biasp[dir*GP + g*HP + tile*32 + c1];
  }
  float cs0 = 0.f, cs1 = 0.f, hs0 = 0.f, hs1 = 0.f;

  unsigned long long* const myslot =
      hbt + (((size_t)cid*2)*16 + eb)*PAIRS + tile*16 + p2;

  // ---- prologue: vx(t0) -> XS0; prefetch vx(t1); one barrier ----
  unsigned long long vx[13];
  {
    const int t0 = dir ? (grp_len - 1) : 0;
    const unsigned long long* xrow =
        (const unsigned long long*)(xin + ((size_t)t0*B_ + grp*16)*KXP);
    #pragma unroll
    for (int j = 0; j < 13; ++j){
      const int idx = j*256 + tid;
      const int b = idx / 208, qq = idx % 208;
      vx[j] = xrow[(size_t)b*208 + qq];
    }
    #pragma unroll
    for (int j = 0; j < 13; ++j){
      const int idx = j*256 + tid;
      const int b = idx / 208, qq = idx % 208;
      *(unsigned long long*)&XS0[b*XS_STRIDE + qq*4] = vx[j];
    }
    if (grp_len > 1){
      const int t1 = dir ? (grp_len - 2) : 1;
      const unsigned long long* xrow1 =
          (const unsigned long long*)(xin + ((size_t)t1*B_ + grp*16)*KXP);
      #pragma unroll
      for (int j = 0; j < 13; ++j){
        const int idx = j*256 + tid;
        const int b = idx / 208, qq = idx % 208;
        vx[j] = xrow1[(size_t)b*208 + qq];
      }
    }
  }
  __syncthreads();                           // XS0 visible for ss=0

  for (int ss = 0; ss < grp_len; ++ss){
    const int t = dir ? (grp_len - 1 - ss) : ss;
    unsigned short* XSb = (ss & 1) ? XS1 : XS0;
    unsigned short* XSn = (ss & 1) ? XS0 : XS1;

    // ---- issue h tag-loads, sample 1 (in flight during x-MFMAs) ----
    const unsigned rtag = (unsigned)ss;
    const unsigned long long* hb =
        hbt + ((size_t)(cid*2 + (ss & 1))*16)*PAIRS;
    unsigned long long v[13];
    #pragma unroll
    for (int j = 0; j < 13; ++j)
      v[j] = h_load_u64(hb + j*256 + tid);

    // ---- 52 x-side MFMAs (read XS[par]) ----
    f32x4 a0 = (f32x4){0.f,0.f,0.f,0.f}, a1 = (f32x4){0.f,0.f,0.f,0.f};
    {
      const int abx = lr*XS_STRIDE + lk*8;
      #pragma unroll
      for (int kk = 0; kk < 26; ++kk){
        bf16x8 xa = __builtin_bit_cast(bf16x8, *(const us8*)&XSb[abx + kk*32]);
        a0 = __builtin_amdgcn_mfma_f32_16x16x32_bf16(xa, Wf0[kk], a0, 0, 0, 0);
        a1 = __builtin_amdgcn_mfma_f32_16x16x32_bf16(xa, Wf1[kk], a1, 0, 0, 0);
      }
    }
    // ---- write XS[par^1] from prefetched vx (data for step ss+1) ----
    if (ss + 1 < grp_len){
      #pragma unroll
      for (int j = 0; j < 13; ++j){
        const int idx = j*256 + tid;
        const int b = idx / 208, qq = idx % 208;
        *(unsigned long long*)&XSn[b*XS_STRIDE + qq*4] = vx[j];
      }
    }
    // ---- prefetch vx for step ss+2 (1.5 steps of flight time) ----
    if (ss + 2 < grp_len){
      const int tn = dir ? (grp_len - 3 - ss) : (ss + 2);
      const unsigned long long* xrow =
          (const unsigned long long*)(xin + ((size_t)tn*B_ + grp*16)*KXP);
      #pragma unroll
      for (int j = 0; j < 13; ++j){
        const int idx = j*256 + tid;
        const int b = idx / 208, qq = idx % 208;
        vx[j] = xrow[(size_t)b*208 + qq];
      }
    }

    // ---- validate/retry h; write HS ----
    {
      unsigned stale = 0;
      #pragma unroll
      for (int j = 0; j < 13; ++j)
        if ((unsigned)(v[j] >> 32) != rtag) stale |= 1u << j;
      while (stale){
        const unsigned m = stale;
        #pragma unroll
        for (int j = 0; j < 13; ++j)
          if (m & (1u << j)) v[j] = h_load_u64(hb + j*256 + tid);
        #pragma unroll
        for (int j = 0; j < 13; ++j)
          if ((m & (1u << j)) && (unsigned)(v[j] >> 32) == rtag) stale &= ~(1u << j);
      }
      #pragma unroll
      for (int j = 0; j < 13; ++j){
        const int idx = j*256 + tid;
        const int b = idx / PAIRS, p = idx % PAIRS;
        *(unsigned*)&HS[b*424 + 2*p] = (unsigned)v[j];
      }
    }
    __syncthreads();                         // B: HS + XS[par^1] visible

    // ---- 26 h-side MFMAs ----
    {
      const int ab = lr*424 + lk*8;
      #pragma unroll
      for (int kk = 0; kk < 13; ++kk){
        bf16x8 av = __builtin_bit_cast(bf16x8, *(const us8*)&HS[ab + kk*32]);
        a0 = __builtin_amdgcn_mfma_f32_16x16x32_bf16(av, Bf0[kk], a0, 0, 0, 0);
        a1 = __builtin_amdgcn_mfma_f32_16x16x32_bf16(av, Bf1[kk], a1, 0, 0, 0);
      }
    }
    // ---- publish gate partials to GC ----
    {
      float* Gw = GC + w * GC_FSTRIDE;
      #pragma unroll
      for (int r = 0; r < 4; ++r){
        Gw[(lk*4 + r)*36 + lr]      = a0[r];
        Gw[(lk*4 + r)*36 + 16 + lr] = a1[r];
      }
    }
    __syncthreads();                         // C: GC visible

    // ---- elementwise LSTM cell ----
    const bool act = t < mylen;
    {
      const float gi0 = GC[0*GC_FSTRIDE + eb*36 + c0] + b0g[0];
      const float gf0 = GC[1*GC_FSTRIDE + eb*36 + c0] + b0g[1];
      const float gg0 = GC[2*GC_FSTRIDE + eb*36 + c0] + b0g[2];
      const float go0 = GC[3*GC_FSTRIDE + eb*36 + c0] + b0g[3];
      const float gi1 = GC[0*GC_FSTRIDE + eb*36 + c1] + b1g[0];
      const float gf1 = GC[1*GC_FSTRIDE + eb*36 + c1] + b1g[1];
      const float gg1 = GC[2*GC_FSTRIDE + eb*36 + c1] + b1g[2];
      const float go1 = GC[3*GC_FSTRIDE + eb*36 + c1] + b1g[3];
      const float cn0 = sigm(gf0)*cs0 + sigm(gi0)*tanh_f(gg0);
      const float hn0 = sigm(go0) * tanh_f(cn0);
      const float cn1 = sigm(gf1)*cs1 + sigm(gi1)*tanh_f(gg1);
      const float hn1 = sigm(go1) * tanh_f(cn1);
      if (act){ cs0 = cn0; hs0 = hn0; cs1 = cn1; hs1 = hn1; }
    }
    // ---- publish tagged h (frozen if masked) into next parity slot ----
    {
      const unsigned hu = (unsigned)f2bf(hs0) | ((unsigned)f2bf(hs1) << 16);
      const unsigned long long hv =
          (unsigned long long)hu | ((unsigned long long)(unsigned)(ss + 1) << 32);
      h_store_u64(myslot + ((size_t)((ss + 1) & 1))*16*PAIRS, hv);
    }
    // ---- layer outputs ----
    if (act){
      const int bg = grp*16 + eb;
      const int hc = tile*32 + c0;
      if constexpr (LAST){
        float* op = out + ((size_t)t*B_ + bg)*800 + dir*H_ + hc;
        if (hc < H_)     op[0] = hs0;
        if (hc + 1 < H_) op[1] = hs1;
      } else {
        const unsigned hu = (unsigned)f2bf(hs0) | ((unsigned)f2bf(hs1) << 16);
        *(unsigned*)(xn + ((size_t)t*B_ + bg)*KXP + (size_t)dir*HP + hc) = hu;
      }
    }
  }
}

// ======================= host side =======================
static void run_all(void* const* din, float* out, char* ws, hipStream_t stream)
{
  const float* x      = (const float*)din[0];
  const int* lens     = (const int*)din[1];
  const float* wihf0  = (const float*)din[2];
  const float* wihf12 = (const float*)din[3];
  const float* whhf   = (const float*)din[4];
  const float* bsf    = (const float*)din[5];
  const float* wihb0  = (const float*)din[6];
  const float* wihb12 = (const float*)din[7];
  const float* whhb   = (const float*)din[8];
  const float* bsb    = (const float*)din[9];

  char* p = ws;
  auto alloc = [&](size_t n){ char* r = p; p += (n + 255) & ~(size_t)255; return r; };
  unsigned short* xA = (unsigned short*)alloc((size_t)T_*B_*KXP*2);
  unsigned short* xB = (unsigned short*)alloc((size_t)T_*B_*KXP*2);
  unsigned short* wihR = (unsigned short*)alloc(WIHR_BYTES);
  unsigned short* whhR = (unsigned short*)alloc(WHHR_BYTES);
  float* biasp       = (float*)alloc((size_t)NW*4);
  unsigned long long* hbt = (unsigned long long*)alloc(HBT_BYTES);

  hipMemsetAsync(out, 0, (size_t)T_*B_*800*4, stream);
  {
    size_t n = (size_t)T_*B_*KXP;
    k_conv_x0<<<dim3((unsigned)((n+255)/256)), dim3(256), 0, stream>>>(x, xA);
  }
  hipFuncSetAttribute(reinterpret_cast<const void*>(&lstm_rec<false>),
                      hipFuncAttributeMaxDynamicSharedMemorySize, LDS_TOTAL);
  hipFuncSetAttribute(reinterpret_cast<const void*>(&lstm_rec<true>),
                      hipFuncAttributeMaxDynamicSharedMemorySize, LDS_TOTAL);

  const unsigned short* xinv[3] = {xA, xB, xA};
  unsigned short* xoutv[3] = {xB, xA, nullptr};

  for (int lyr = 0; lyr < 3; ++lyr){
    const float* wf = (lyr == 0) ? wihf0 : wihf12 + (size_t)(lyr-1)*1600*800;
    const float* wb = (lyr == 0) ? wihb0 : wihb12 + (size_t)(lyr-1)*1600*800;
    {
      size_t n = WIHR_US8;
      k_prep_wihR<<<dim3((unsigned)((n+255)/256)), dim3(256), 0, stream>>>(
          wf, wb, lyr ? 1 : 0, wihR);
    }
    k_prep_bias<<<dim3((NW+255)/256), dim3(256), 0, stream>>>(
        bsf + (size_t)lyr*1600, bsb + (size_t)lyr*1600, biasp);
    {
      size_t n = WHHR_US8;
      k_prep_whhR<<<dim3((unsigned)((n+255)/256)), dim3(256), 0, stream>>>(
          whhf + (size_t)lyr*1600*400, whhb + (size_t)lyr*1600*400, whhR);
    }
    hipMemsetAsync(hbt, 0, HBT_BYTES, stream);

    if (lyr < 2)
      lstm_rec<false><<<dim3(REC_BLOCKS), dim3(256), LDS_TOTAL, stream>>>(
          xinv[lyr], wihR, whhR, biasp, lens, hbt, xoutv[lyr], out);
    else
      lstm_rec<true><<<dim3(REC_BLOCKS), dim3(256), LDS_TOTAL, stream>>>(
          xinv[lyr], wihR, whhR, biasp, lens, hbt, nullptr, out);
  }
}

extern "C" void kernel_launch(void* const* d_in, const int* in_sizes, int n_in,
                              void* d_out, int out_size, void* d_ws, size_t ws_size,
                              hipStream_t stream)
{
  (void)in_sizes; (void)n_in; (void)out_size;
  auto align = [](size_t n){ return (n + 255) & ~(size_t)255; };
  const size_t need =
      align((size_t)T_*B_*KXP*2) * 2 +
      align(WIHR_BYTES) +
      align(WHHR_BYTES) +
      align((size_t)NW*4) +
      align(HBT_BYTES);

  if (ws_size >= need)
    run_all(d_in, (float*)d_out, (char*)d_ws, stream);
  else
    hipMemsetAsync(d_out, 0, (size_t)T_*B_*800*4, stream);
}

// Round 18
// 5168.354 us; speedup vs baseline: 2.1108x; 1.2220x over previous
//
#include <hip/hip_runtime.h>
#include <stdint.h>
#include <stddef.h>

#define T_ 512
#define B_ 128
#define D_ 400
#define H_ 400
#define HP 416
#define GP 1664            // 4*HP (per-dir padded gate dim)
#define NW 3328            // both dirs stacked
#define KXP 832            // uniform padded x-K for all layers
#define NTILES 13          // h tiles of 32 per dir
#define NGRP 8             // batch groups of 16
#define REC_BLOCKS 208     // 2*8*13
#define PAIRS 208          // 416 cols / 2 per batch row (u64 slots)

// GC float stride
#define GC_FSTRIDE 576     // 16*36

// rec LDS layout (dynamic): HS | XS[2] | GC
#define HS_BYTES  (16*424*2)                 // 13568
#define XS_STRIDE 840
#define XS_BYTES  (16*XS_STRIDE*2)           // 26880
#define XS0_OFF   HS_BYTES
#define XS1_OFF   (HS_BYTES + XS_BYTES)
#define GC_OFF    (HS_BYTES + 2*XS_BYTES)    // 67328
#define LDS_TOTAL (GC_OFF + 4*GC_FSTRIDE*4)  // 76544

// tagged h buffer: [16 cid][2 parity][16 batch][208 pair] u64
#define HBT_U64   ((size_t)16*2*16*PAIRS)
#define HBT_BYTES (HBT_U64*8)

// Whh register-fragment blob: [2 dir][13 tile][4 gate][2 ch][13 kk][64 lane][8]
#define WHHR_US8  ((size_t)2*13*4*2*13*64)
#define WHHR_BYTES (WHHR_US8*8*2)
// Wih register-fragment blob: [2 dir][13 tile][4 gate][2 ch][26 kk][64 lane][8]
#define WIHR_US8  ((size_t)2*13*4*2*26*64)
#define WIHR_BYTES (WIHR_US8*8*2)

typedef __attribute__((ext_vector_type(8))) __bf16 bf16x8;
typedef __attribute__((ext_vector_type(4))) float f32x4;
typedef __attribute__((ext_vector_type(8))) unsigned short us8;

__device__ __forceinline__ unsigned short f2bf(float f){
  unsigned u = __builtin_bit_cast(unsigned, f);
  u = (u + 0x7FFFu + ((u >> 16) & 1u)) >> 16;
  return (unsigned short)u;
}
__device__ __forceinline__ float bf2f(unsigned short s){
  unsigned u = ((unsigned)s) << 16;
  return __builtin_bit_cast(float, u);
}
__device__ __forceinline__ float sigm(float x){ return 1.f / (1.f + __expf(-x)); }
__device__ __forceinline__ float tanh_f(float x){
  float ax = fabsf(x);
  float e = __expf(-2.f * ax);
  float t = (1.f - e) / (1.f + e);
  return x < 0.f ? -t : t;
}

// agent-scope relaxed atomics == MALL-coherent accesses, NO cache maintenance
__device__ __forceinline__ void h_store_u64(unsigned long long* p, unsigned long long v){
  __hip_atomic_store(p, v, __ATOMIC_RELAXED, __HIP_MEMORY_SCOPE_AGENT);
}
__device__ __forceinline__ unsigned long long h_load_u64(const unsigned long long* p){
  return __hip_atomic_load(p, __ATOMIC_RELAXED, __HIP_MEMORY_SCOPE_AGENT);
}

// ======================= prep kernels =======================
__global__ void k_conv_x0(const float* __restrict__ x, unsigned short* __restrict__ xa){
  const size_t i = (size_t)blockIdx.x*256 + threadIdx.x;
  if (i >= (size_t)T_*B_*KXP) return;
  const int k = (int)(i % KXP);
  const size_t tb = i / KXP;
  xa[i] = f2bf(k < D_ ? x[tb*D_ + k] : 0.f);
}

// Wih -> MFMA B-fragments [2 dir][13 tile][4 gate][2 ch][26 kk][64 lane][8]
__global__ void k_prep_wihR(const float* __restrict__ wf, const float* __restrict__ wb,
                            int mode, unsigned short* __restrict__ dst){
  const size_t i = (size_t)blockIdx.x*256 + threadIdx.x;
  if (i >= WIHR_US8) return;
  const int lane = (int)(i & 63);
  size_t q = i >> 6;
  const int kk = (int)(q % 26); q /= 26;
  const int ch = (int)(q % 2);  q /= 2;
  const int g  = (int)(q % 4);  q /= 4;
  const int tile = (int)(q % 13);
  const int dirx = (int)(q / 13);
  const int c  = tile*32 + ch*16 + (lane & 15);
  const int k0 = kk*32 + (lane >> 4)*8;
  const float* W = dirx ? wb : wf;
  const int stride = mode ? 800 : D_;
  unsigned short v[8];
  #pragma unroll
  for (int e = 0; e < 8; ++e){
    const int k = k0 + e;
    int ks;
    if (mode == 0) ks = (k < D_) ? k : -1;
    else           ks = (k < 400) ? k : ((k >= 416 && k < 816) ? (k - 16) : -1);
    const float x = (c < H_ && ks >= 0) ? W[(size_t)(g*H_ + c)*stride + ks] : 0.f;
    v[e] = f2bf(x);
  }
  *(us8*)(dst + i*8) = *(const us8*)v;
}

// Whh -> B-fragments (R7-verified layout)
__global__ void k_prep_whhR(const float* __restrict__ wf, const float* __restrict__ wb,
                            unsigned short* __restrict__ dst){
  const size_t i = (size_t)blockIdx.x*256 + threadIdx.x;
  if (i >= WHHR_US8) return;
  const int lane = (int)(i & 63);
  size_t q = i >> 6;
  const int kk = (int)(q % 13); q /= 13;
  const int ch = (int)(q % 2);  q /= 2;
  const int w  = (int)(q % 4);  q /= 4;
  const int tile = (int)(q % 13);
  const int dirx = (int)(q / 13);
  const int c  = tile*32 + ch*16 + (lane & 15);
  const int k0 = kk*32 + (lane >> 4)*8;
  const float* W = dirx ? wb : wf;
  unsigned short v[8];
  #pragma unroll
  for (int e = 0; e < 8; ++e){
    const int k = k0 + e;
    const float x = (c < H_ && k < H_) ? W[(size_t)(w*H_ + c)*H_ + k] : 0.f;
    v[e] = f2bf(x);
  }
  *(us8*)(dst + i*8) = *(const us8*)v;
}

__global__ void k_prep_bias(const float* __restrict__ bsf, const float* __restrict__ bsb,
                            float* __restrict__ dst){
  const int n = blockIdx.x*256 + threadIdx.x;
  if (n >= NW) return;
  const int d = n / GP, ng = n % GP, g = ng / HP, r = ng % HP;
  dst[n] = (r < H_) ? (d ? bsb : bsf)[g*H_ + r] : 0.f;
}

// ======================= recurrent (R13 + retry backoff) =================
// grid: 208 blocks = dir(2) x group(8 of 16 batches) x htile(13 of 32 cols)
// R13 schedule (proven 5120us): write XS[par] (vx prefetched last step) ->
// prefetch vx(s+1) -> barrier A -> issue h tag-loads -> 52 x-MFMAs (loads
// in flight) -> validate/retry -> HS -> barrier B -> 26 h-MFMAs -> GC ->
// barrier C -> cell -> tagged publish. Single delta vs R13: s_sleep(4)
// backoff AFTER a failed retry (first retry immediate) — spaces retry-load
// storms contending with publishes at the MALL. Zero numerics/regs impact.
template<bool LAST>
__global__ __launch_bounds__(256, 1) void lstm_rec(
    const unsigned short* __restrict__ xin,    // [T][128][832] bf16
    const unsigned short* __restrict__ wihR,   // Wih fragments
    const unsigned short* __restrict__ whhR,   // Whh fragments
    const float* __restrict__ biasp,           // [NW] f32
    const int* __restrict__ lens,
    unsigned long long* hbt,                   // tagged h (host-zeroed)
    unsigned short* __restrict__ xn,           // [T][128][832] bf16 (or unused)
    float* __restrict__ out)                   // [T][128][800] f32 (or unused)
{
  extern __shared__ char smem[];
  unsigned short* HS = (unsigned short*)smem;                // [16][424]
  unsigned short* XS0 = (unsigned short*)(smem + XS0_OFF);   // [16][840]
  unsigned short* XS1 = (unsigned short*)(smem + XS1_OFF);   // [16][840]
  float* GC = (float*)(smem + GC_OFF);                       // [4][576]

  const int tid = threadIdx.x;
  const int bid = blockIdx.x;
  const int dir  = bid / 104;
  const int rem  = bid % 104;
  const int grp  = rem / NTILES;
  const int tile = rem % NTILES;
  const int l  = tid & 63;
  const int w  = tid >> 6;
  const int lr = l & 15;
  const int lk = l >> 4;
  const int cid = dir*NGRP + grp;

  // Whh B-fragments -> 104 regs (loop-invariant)
  us8 Bf0[13], Bf1[13];
  {
    const unsigned short* bs =
        whhR + ((size_t)((dir*13 + tile)*4 + w)*2*13*64 + l)*8;
    #pragma unroll
    for (int kk = 0; kk < 13; ++kk)
      Bf0[kk] = *(const us8*)(bs + (size_t)kk*512);
    const unsigned short* bs1 = bs + (size_t)13*64*8;
    #pragma unroll
    for (int kk = 0; kk < 13; ++kk)
      Bf1[kk] = *(const us8*)(bs1 + (size_t)kk*512);
  }
  // Wih B-fragments -> 208 regs (loop-invariant)
  us8 Wf0[26], Wf1[26];
  {
    const unsigned short* ws0 =
        wihR + ((size_t)(((dir*13 + tile)*4 + w)*2 + 0)*26*64 + l)*8;
    #pragma unroll
    for (int kk = 0; kk < 26; ++kk)
      Wf0[kk] = *(const us8*)(ws0 + (size_t)kk*512);
    const unsigned short* ws1 = ws0 + (size_t)26*64*8;
    #pragma unroll
    for (int kk = 0; kk < 26; ++kk)
      Wf1[kk] = *(const us8*)(ws1 + (size_t)kk*512);
  }

  const int grp_len = lens[grp*16];          // lens sorted desc -> group max
  const int eb  = tid & 15;                  // elementwise batch
  const int p2  = tid >> 4;                  // col pair within tile
  const int mylen = lens[grp*16 + eb];
  const int c0 = 2*p2, c1 = 2*p2 + 1;
  float b0g[4], b1g[4];
  #pragma unroll
  for (int g = 0; g < 4; ++g){
    b0g[g] = biasp[dir*GP + g*HP + tile*32 + c0];
    b1g[g] = biasp[dir*GP + g*HP + tile*32 + c1];
  }
  float cs0 = 0.f, cs1 = 0.f, hs0 = 0.f, hs1 = 0.f;
  __syncthreads();

  unsigned long long* const myslot =
      hbt + (((size_t)cid*2)*16 + eb)*PAIRS + tile*16 + p2;

  // ---- prologue: load vx for step 0 ----
  unsigned long long vx[13];
  {
    const int t0 = dir ? (grp_len - 1) : 0;
    const unsigned long long* xrow =
        (const unsigned long long*)(xin + ((size_t)t0*B_ + grp*16)*KXP);
    #pragma unroll
    for (int j = 0; j < 13; ++j){
      const int idx = j*256 + tid;
      const int b = idx / 208, qq = idx % 208;
      vx[j] = xrow[(size_t)b*208 + qq];
    }
  }

  for (int ss = 0; ss < grp_len; ++ss){
    const int t = dir ? (grp_len - 1 - ss) : ss;
    unsigned short* XSb = (ss & 1) ? XS1 : XS0;

    // ---- write XS[par] from prefetched vx ----
    #pragma unroll
    for (int j = 0; j < 13; ++j){
      const int idx = j*256 + tid;
      const int b = idx / 208, qq = idx % 208;
      *(unsigned long long*)&XSb[b*XS_STRIDE + qq*4] = vx[j];
    }
    // ---- prefetch vx for step ss+1 (flies across the whole step) ----
    if (ss + 1 < grp_len){
      const int tn = dir ? (grp_len - 2 - ss) : (ss + 1);
      const unsigned long long* xrow =
          (const unsigned long long*)(xin + ((size_t)tn*B_ + grp*16)*KXP);
      #pragma unroll
      for (int j = 0; j < 13; ++j){
        const int idx = j*256 + tid;
        const int b = idx / 208, qq = idx % 208;
        vx[j] = xrow[(size_t)b*208 + qq];
      }
    }
    __syncthreads();                         // A: XS[par] visible

    // ---- issue h tag-loads, sample 1 (in flight during x-MFMAs) ----
    const unsigned rtag = (unsigned)ss;
    const unsigned long long* hb =
        hbt + ((size_t)(cid*2 + (ss & 1))*16)*PAIRS;
    unsigned long long v[13];
    #pragma unroll
    for (int j = 0; j < 13; ++j)
      v[j] = h_load_u64(hb + j*256 + tid);

    // ---- 52 x-side MFMAs (independent of exchange) ----
    f32x4 a0 = (f32x4){0.f,0.f,0.f,0.f}, a1 = (f32x4){0.f,0.f,0.f,0.f};
    {
      const int abx = lr*XS_STRIDE + lk*8;
      #pragma unroll
      for (int kk = 0; kk < 26; ++kk){
        bf16x8 xa = __builtin_bit_cast(bf16x8, *(const us8*)&XSb[abx + kk*32]);
        a0 = __builtin_amdgcn_mfma_f32_16x16x32_bf16(xa, Wf0[kk], a0, 0, 0, 0);
        a1 = __builtin_amdgcn_mfma_f32_16x16x32_bf16(xa, Wf1[kk], a1, 0, 0, 0);
      }
    }
    // ---- validate/retry h; write HS ----
    {
      unsigned stale = 0;
      #pragma unroll
      for (int j = 0; j < 13; ++j)
        if ((unsigned)(v[j] >> 32) != rtag) stale |= 1u << j;
      while (stale){
        const unsigned m = stale;
        #pragma unroll
        for (int j = 0; j < 13; ++j)
          if (m & (1u << j)) v[j] = h_load_u64(hb + j*256 + tid);
        #pragma unroll
        for (int j = 0; j < 13; ++j)
          if ((m & (1u << j)) && (unsigned)(v[j] >> 32) == rtag) stale &= ~(1u << j);
        if (stale) __builtin_amdgcn_s_sleep(4);   // backoff after failed retry
      }
      #pragma unroll
      for (int j = 0; j < 13; ++j){
        const int idx = j*256 + tid;
        const int b = idx / PAIRS, p = idx % PAIRS;
        *(unsigned*)&HS[b*424 + 2*p] = (unsigned)v[j];
      }
    }
    __syncthreads();                         // B: HS visible

    // ---- 26 h-side MFMAs ----
    {
      const int ab = lr*424 + lk*8;
      #pragma unroll
      for (int kk = 0; kk < 13; ++kk){
        bf16x8 av = __builtin_bit_cast(bf16x8, *(const us8*)&HS[ab + kk*32]);
        a0 = __builtin_amdgcn_mfma_f32_16x16x32_bf16(av, Bf0[kk], a0, 0, 0, 0);
        a1 = __builtin_amdgcn_mfma_f32_16x16x32_bf16(av, Bf1[kk], a1, 0, 0, 0);
      }
    }
    // ---- publish gate partials to GC ----
    {
      float* Gw = GC + w * GC_FSTRIDE;
      #pragma unroll
      for (int r = 0; r < 4; ++r){
        Gw[(lk*4 + r)*36 + lr]      = a0[r];
        Gw[(lk*4 + r)*36 + 16 + lr] = a1[r];
      }
    }
    __syncthreads();                         // C: GC visible

    // ---- elementwise LSTM cell ----
    const bool act = t < mylen;
    {
      const float gi0 = GC[0*GC_FSTRIDE + eb*36 + c0] + b0g[0];
      const float gf0 = GC[1*GC_FSTRIDE + eb*36 + c0] + b0g[1];
      const float gg0 = GC[2*GC_FSTRIDE + eb*36 + c0] + b0g[2];
      const float go0 = GC[3*GC_FSTRIDE + eb*36 + c0] + b0g[3];
      const float gi1 = GC[0*GC_FSTRIDE + eb*36 + c1] + b1g[0];
      const float gf1 = GC[1*GC_FSTRIDE + eb*36 + c1] + b1g[1];
      const float gg1 = GC[2*GC_FSTRIDE + eb*36 + c1] + b1g[2];
      const float go1 = GC[3*GC_FSTRIDE + eb*36 + c1] + b1g[3];
      const float cn0 = sigm(gf0)*cs0 + sigm(gi0)*tanh_f(gg0);
      const float hn0 = sigm(go0) * tanh_f(cn0);
      const float cn1 = sigm(gf1)*cs1 + sigm(gi1)*tanh_f(gg1);
      const float hn1 = sigm(go1) * tanh_f(cn1);
      if (act){ cs0 = cn0; hs0 = hn0; cs1 = cn1; hs1 = hn1; }
    }
    // ---- publish tagged h (frozen if masked) into next parity slot ----
    {
      const unsigned hu = (unsigned)f2bf(hs0) | ((unsigned)f2bf(hs1) << 16);
      const unsigned long long hv =
          (unsigned long long)hu | ((unsigned long long)(unsigned)(ss + 1) << 32);
      h_store_u64(myslot + ((size_t)((ss + 1) & 1))*16*PAIRS, hv);
    }
    // ---- layer outputs ----
    if (act){
      const int bg = grp*16 + eb;
      const int hc = tile*32 + c0;
      if constexpr (LAST){
        float* op = out + ((size_t)t*B_ + bg)*800 + dir*H_ + hc;
        if (hc < H_)     op[0] = hs0;
        if (hc + 1 < H_) op[1] = hs1;
      } else {
        const unsigned hu = (unsigned)f2bf(hs0) | ((unsigned)f2bf(hs1) << 16);
        *(unsigned*)(xn + ((size_t)t*B_ + bg)*KXP + (size_t)dir*HP + hc) = hu;
      }
    }
  }
}

// ======================= host side =======================
static void run_all(void* const* din, float* out, char* ws, hipStream_t stream)
{
  const float* x      = (const float*)din[0];
  const int* lens     = (const int*)din[1];
  const float* wihf0  = (const float*)din[2];
  const float* wihf12 = (const float*)din[3];
  const float* whhf   = (const float*)din[4];
  const float* bsf    = (const float*)din[5];
  const float* wihb0  = (const float*)din[6];
  const float* wihb12 = (const float*)din[7];
  const float* whhb   = (const float*)din[8];
  const float* bsb    = (const float*)din[9];

  char* p = ws;
  auto alloc = [&](size_t n){ char* r = p; p += (n + 255) & ~(size_t)255; return r; };
  unsigned short* xA = (unsigned short*)alloc((size_t)T_*B_*KXP*2);
  unsigned short* xB = (unsigned short*)alloc((size_t)T_*B_*KXP*2);
  unsigned short* wihR = (unsigned short*)alloc(WIHR_BYTES);
  unsigned short* whhR = (unsigned short*)alloc(WHHR_BYTES);
  float* biasp       = (float*)alloc((size_t)NW*4);
  unsigned long long* hbt = (unsigned long long*)alloc(HBT_BYTES);

  hipMemsetAsync(out, 0, (size_t)T_*B_*800*4, stream);
  {
    size_t n = (size_t)T_*B_*KXP;
    k_conv_x0<<<dim3((unsigned)((n+255)/256)), dim3(256), 0, stream>>>(x, xA);
  }
  hipFuncSetAttribute(reinterpret_cast<const void*>(&lstm_rec<false>),
                      hipFuncAttributeMaxDynamicSharedMemorySize, LDS_TOTAL);
  hipFuncSetAttribute(reinterpret_cast<const void*>(&lstm_rec<true>),
                      hipFuncAttributeMaxDynamicSharedMemorySize, LDS_TOTAL);

  const unsigned short* xinv[3] = {xA, xB, xA};
  unsigned short* xoutv[3] = {xB, xA, nullptr};

  for (int lyr = 0; lyr < 3; ++lyr){
    const float* wf = (lyr == 0) ? wihf0 : wihf12 + (size_t)(lyr-1)*1600*800;
    const float* wb = (lyr == 0) ? wihb0 : wihb12 + (size_t)(lyr-1)*1600*800;
    {
      size_t n = WIHR_US8;
      k_prep_wihR<<<dim3((unsigned)((n+255)/256)), dim3(256), 0, stream>>>(
          wf, wb, lyr ? 1 : 0, wihR);
    }
    k_prep_bias<<<dim3((NW+255)/256), dim3(256), 0, stream>>>(
        bsf + (size_t)lyr*1600, bsb + (size_t)lyr*1600, biasp);
    {
      size_t n = WHHR_US8;
      k_prep_whhR<<<dim3((unsigned)((n+255)/256)), dim3(256), 0, stream>>>(
          whhf + (size_t)lyr*1600*400, whhb + (size_t)lyr*1600*400, whhR);
    }
    hipMemsetAsync(hbt, 0, HBT_BYTES, stream);

    if (lyr < 2)
      lstm_rec<false><<<dim3(REC_BLOCKS), dim3(256), LDS_TOTAL, stream>>>(
          xinv[lyr], wihR, whhR, biasp, lens, hbt, xoutv[lyr], out);
    else
      lstm_rec<true><<<dim3(REC_BLOCKS), dim3(256), LDS_TOTAL, stream>>>(
          xinv[lyr], wihR, whhR, biasp, lens, hbt, nullptr, out);
  }
}

extern "C" void kernel_launch(void* const* d_in, const int* in_sizes, int n_in,
                              void* d_out, int out_size, void* d_ws, size_t ws_size,
                              hipStream_t stream)
{
  (void)in_sizes; (void)n_in; (void)out_size;
  auto align = [](size_t n){ return (n + 255) & ~(size_t)255; };
  const size_t need =
      align((size_t)T_*B_*KXP*2) * 2 +
      align(WIHR_BYTES) +
      align(WHHR_BYTES) +
      align((size_t)NW*4) +
      align(HBT_BYTES);

  if (ws_size >= need)
    run_all(d_in, (float*)d_out, (char*)d_ws, stream);
  else
    hipMemsetAsync(d_out, 0, (size_t)T_*B_*800*4, stream);
}